// Round 1
// baseline (197.565 us; speedup 1.0000x reference)
//
#include <hip/hip_runtime.h>
#include <hip/hip_bf16.h>

#define B_ 2
#define H_ 8
#define S_ 2048
#define D_ 64
#define R_ 128

typedef __bf16 bf16x8 __attribute__((ext_vector_type(8)));
typedef unsigned short u16x8 __attribute__((ext_vector_type(8)));
typedef float f32x4 __attribute__((ext_vector_type(4)));

__device__ __forceinline__ unsigned short f2bf(float f) {
  union { float f; unsigned u; } x; x.f = f;
  unsigned r = x.u + 0x7fffu + ((x.u >> 16) & 1u);
  return (unsigned short)(r >> 16);
}
__device__ __forceinline__ float bf2f(unsigned short s) {
  union { unsigned u; float f; } x; x.u = ((unsigned)s) << 16;
  return x.f;
}

// One workgroup = 4 waves, handles 64 q-rows of one (b,h). Flash loop over K/V
// tiles of 64. All matmuls in bf16 MFMA (16x16x32), softmax/accum in fp32.
__launch_bounds__(256, 2)
__global__ void relattn_kernel(const float* __restrict__ qg,
                               const float* __restrict__ kg,
                               const float* __restrict__ vg,
                               const float* __restrict__ rel,
                               const int* __restrict__ qinfo,
                               const int* __restrict__ kinfo,
                               float* __restrict__ out) {
  // kq_lds: Q during setup, then K tiles (reuse keeps static LDS < 64 KB)
  __shared__ __align__(16) unsigned short kq_lds[64 * 64];
  __shared__ __align__(16) unsigned short vt_lds[64 * 64];   // V transposed [d][k]
  __shared__ __align__(16) unsigned short p_lds[4 * 16 * 64];
  __shared__ __align__(16) unsigned short qr_lds[64 * 272];  // bias table, bf16
  __shared__ int kadj_lds[64];
  __shared__ int qadj_lds[64];

  const int t = threadIdx.x;
  const int lane = t & 63;
  const int w = t >> 6;
  const int lr = lane & 15;
  const int lg = lane >> 4;
  const int qb = blockIdx.x;
  const int bh = blockIdx.y;
  const int b = bh >> 3;  // H_ = 8

  const float* qbase = qg + ((size_t)bh * S_ + (size_t)qb * 64) * D_;
  const float* kbase = kg + (size_t)bh * S_ * D_;
  const float* vbase = vg + (size_t)bh * S_ * D_;

  // ---- stage Q tile (64x64) to LDS as bf16, XOR-swizzled rows ----
#pragma unroll
  for (int p = 0; p < 4; ++p) {
    int row = p * 16 + (t >> 4);
    int col = (t & 15) * 4;
    const float4 f = *(const float4*)(qbase + row * 64 + col);
    ushort4 u = make_ushort4(f2bf(f.x), f2bf(f.y), f2bf(f.z), f2bf(f.w));
    *(ushort4*)(&kq_lds[row * 64 + (col ^ ((row & 7) << 3))]) = u;
  }
  if (t < 64) {
    int qa = qinfo[b * S_ + qb * 64 + t];
    qadj_lds[t] = (qa == -1) ? 2 * R_ : qa;
  }
  __syncthreads();

  // ---- load Q A-fragments (kept in registers for the whole kernel) ----
  bf16x8 qa0, qa1;
  {
    const unsigned short* rbase = &kq_lds[(w * 16 + lr) * 64];
    qa0 = *(const bf16x8*)(rbase + ((8 * lg) ^ ((lr & 7) << 3)));
    qa1 = *(const bf16x8*)(rbase + ((32 + 8 * lg) ^ ((lr & 7) << 3)));
  }
  int qadj_r[4];
#pragma unroll
  for (int j = 0; j < 4; ++j) qadj_r[j] = qadj_lds[w * 16 + 4 * lg + j];
  const int qr_rowbase = (w * 16 + 4 * lg) * 272;

  // ---- qr tile = Q @ rel^T  (64 x 257) via MFMA, store bf16 to LDS ----
#pragma unroll 1
  for (int rt = 0; rt < 17; ++rt) {
    int r = rt * 16 + lr;
    u16x8 t0 = {0, 0, 0, 0, 0, 0, 0, 0};
    u16x8 t1 = {0, 0, 0, 0, 0, 0, 0, 0};
    if (r < 257) {
      const float* rp = rel + r * 64 + 8 * lg;
      float4 fa = *(const float4*)(rp);
      float4 fb = *(const float4*)(rp + 4);
      float4 fc = *(const float4*)(rp + 32);
      float4 fd = *(const float4*)(rp + 36);
      t0 = (u16x8){f2bf(fa.x), f2bf(fa.y), f2bf(fa.z), f2bf(fa.w),
                   f2bf(fb.x), f2bf(fb.y), f2bf(fb.z), f2bf(fb.w)};
      t1 = (u16x8){f2bf(fc.x), f2bf(fc.y), f2bf(fc.z), f2bf(fc.w),
                   f2bf(fd.x), f2bf(fd.y), f2bf(fd.z), f2bf(fd.w)};
    }
    bf16x8 rb0 = __builtin_bit_cast(bf16x8, t0);
    bf16x8 rb1 = __builtin_bit_cast(bf16x8, t1);
    f32x4 acc = {0.f, 0.f, 0.f, 0.f};
    acc = __builtin_amdgcn_mfma_f32_16x16x32_bf16(qa0, rb0, acc, 0, 0, 0);
    acc = __builtin_amdgcn_mfma_f32_16x16x32_bf16(qa1, rb1, acc, 0, 0, 0);
#pragma unroll
    for (int j = 0; j < 4; ++j)
      qr_lds[qr_rowbase + j * 272 + rt * 16 + lr] = f2bf(acc[j]);
  }

  // ---- flash loop state ----
  float m_r[4], l_r[4];
  f32x4 o_acc[4];
#pragma unroll
  for (int j = 0; j < 4; ++j) { m_r[j] = -INFINITY; l_r[j] = 0.f; }
#pragma unroll
  for (int dt = 0; dt < 4; ++dt) o_acc[dt] = (f32x4){0.f, 0.f, 0.f, 0.f};

  const float SC = 0.125f * 1.44269504088896340736f;  // 1/sqrt(64) * log2(e)
  unsigned short* p_w = &p_lds[w * 16 * 64];

  for (int kt = 0; kt < 32; ++kt) {
    __syncthreads();  // prior tile fully consumed before overwrite
    // ---- stage K (swizzled rows) and V (transposed [d][k], swizzled) ----
    const float* ksrc = kbase + (size_t)(kt * 64) * 64;
    const float* vsrc = vbase + (size_t)(kt * 64) * 64;
#pragma unroll
    for (int p = 0; p < 4; ++p) {
      int row = p * 16 + (t >> 4);
      int col = (t & 15) * 4;
      float4 f = *(const float4*)(ksrc + row * 64 + col);
      ushort4 u = make_ushort4(f2bf(f.x), f2bf(f.y), f2bf(f.z), f2bf(f.w));
      *(ushort4*)(&kq_lds[row * 64 + (col ^ ((row & 7) << 3))]) = u;
      float4 fv = *(const float4*)(vsrc + row * 64 + col);
      vt_lds[(col + 0) * 64 + (row ^ (((col + 0) & 7) << 3))] = f2bf(fv.x);
      vt_lds[(col + 1) * 64 + (row ^ (((col + 1) & 7) << 3))] = f2bf(fv.y);
      vt_lds[(col + 2) * 64 + (row ^ (((col + 2) & 7) << 3))] = f2bf(fv.z);
      vt_lds[(col + 3) * 64 + (row ^ (((col + 3) & 7) << 3))] = f2bf(fv.w);
    }
    if (t < 64) {
      int ka = kinfo[b * S_ + kt * 64 + t];
      kadj_lds[t] = (ka == -1) ? 3 * R_ : ka;
    }
    __syncthreads();

    // ---- scores: S = Q K^T (wave's 16 q-rows x 64 k-cols) ----
    f32x4 sfr[4];
#pragma unroll
    for (int st = 0; st < 4; ++st) {
      const unsigned short* kb = &kq_lds[(st * 16 + lr) * 64];
      bf16x8 kb0 = *(const bf16x8*)(kb + ((8 * lg) ^ ((lr & 7) << 3)));
      bf16x8 kb1 = *(const bf16x8*)(kb + ((32 + 8 * lg) ^ ((lr & 7) << 3)));
      f32x4 acc = {0.f, 0.f, 0.f, 0.f};
      acc = __builtin_amdgcn_mfma_f32_16x16x32_bf16(qa0, kb0, acc, 0, 0, 0);
      acc = __builtin_amdgcn_mfma_f32_16x16x32_bf16(qa1, kb1, acc, 0, 0, 0);
      sfr[st] = acc;
    }
    // ---- add gathered relative bias, to exp2-domain units ----
    float tv[4][4];
#pragma unroll
    for (int st = 0; st < 4; ++st) {
      int ka = kadj_lds[st * 16 + lr];
#pragma unroll
      for (int j = 0; j < 4; ++j) {
        int dm = ka - qadj_r[j];
        dm = min(max(dm, -R_), R_) + R_;
        float bias = bf2f(qr_lds[qr_rowbase + j * 272 + dm]);
        tv[st][j] = (sfr[st][j] + bias) * SC;
      }
    }
    // ---- online softmax (row reduce over 16 lanes x 4 subtiles) ----
#pragma unroll
    for (int j = 0; j < 4; ++j) {
      float mx = fmaxf(fmaxf(tv[0][j], tv[1][j]), fmaxf(tv[2][j], tv[3][j]));
      mx = fmaxf(mx, __shfl_xor(mx, 1));
      mx = fmaxf(mx, __shfl_xor(mx, 2));
      mx = fmaxf(mx, __shfl_xor(mx, 4));
      mx = fmaxf(mx, __shfl_xor(mx, 8));
      float mnew = fmaxf(m_r[j], mx);
      float scale = exp2f(m_r[j] - mnew);
      float rs = 0.f;
#pragma unroll
      for (int st = 0; st < 4; ++st) {
        float p = exp2f(tv[st][j] - mnew);
        tv[st][j] = p;
        rs += p;
      }
      rs += __shfl_xor(rs, 1);
      rs += __shfl_xor(rs, 2);
      rs += __shfl_xor(rs, 4);
      rs += __shfl_xor(rs, 8);
      l_r[j] = l_r[j] * scale + rs;
      m_r[j] = mnew;
#pragma unroll
      for (int dt = 0; dt < 4; ++dt) o_acc[dt][j] *= scale;
    }
    // ---- P -> LDS (bf16, swizzled) ----
#pragma unroll
    for (int st = 0; st < 4; ++st) {
#pragma unroll
      for (int j = 0; j < 4; ++j) {
        int row = 4 * lg + j;
        int col = st * 16 + lr;
        p_w[row * 64 + (col ^ ((row & 7) << 3))] = f2bf(tv[st][j]);
      }
    }
    // ---- O += P V ----
    bf16x8 pa0, pa1;
    {
      const unsigned short* pb = &p_w[lr * 64];
      pa0 = *(const bf16x8*)(pb + ((8 * lg) ^ ((lr & 7) << 3)));
      pa1 = *(const bf16x8*)(pb + ((32 + 8 * lg) ^ ((lr & 7) << 3)));
    }
#pragma unroll
    for (int dt = 0; dt < 4; ++dt) {
      const unsigned short* vb = &vt_lds[(dt * 16 + lr) * 64];
      bf16x8 vb0 = *(const bf16x8*)(vb + ((8 * lg) ^ ((lr & 7) << 3)));
      bf16x8 vb1 = *(const bf16x8*)(vb + ((32 + 8 * lg) ^ ((lr & 7) << 3)));
      o_acc[dt] = __builtin_amdgcn_mfma_f32_16x16x32_bf16(pa0, vb0, o_acc[dt], 0, 0, 0);
      o_acc[dt] = __builtin_amdgcn_mfma_f32_16x16x32_bf16(pa1, vb1, o_acc[dt], 0, 0, 0);
    }
  }

  // ---- epilogue: O /= l, store fp32 ----
  float* obase = out + ((size_t)bh * S_ + (size_t)(qb * 64 + w * 16)) * 64;
#pragma unroll
  for (int j = 0; j < 4; ++j) {
    float inv = 1.f / l_r[j];
    int row = 4 * lg + j;
#pragma unroll
    for (int dt = 0; dt < 4; ++dt) {
      obase[row * 64 + dt * 16 + lr] = o_acc[dt][j] * inv;
    }
  }
}

extern "C" void kernel_launch(void* const* d_in, const int* in_sizes, int n_in,
                              void* d_out, int out_size, void* d_ws, size_t ws_size,
                              hipStream_t stream) {
  const float* q = (const float*)d_in[0];
  const float* k = (const float*)d_in[1];
  const float* v = (const float*)d_in[2];
  const float* rel = (const float*)d_in[3];
  const int* qi = (const int*)d_in[4];
  const int* ki = (const int*)d_in[5];
  float* out = (float*)d_out;
  dim3 grid(S_ / 64, B_ * H_);
  relattn_kernel<<<grid, dim3(256), 0, stream>>>(q, k, v, rel, qi, ki, out);
}

// Round 5
// 162.794 us; speedup vs baseline: 1.2136x; 1.2136x over previous
//
#include <hip/hip_runtime.h>
#include <hip/hip_bf16.h>

#define B_ 2
#define H_ 8
#define S_ 2048
#define D_ 64
#define R_ 128

typedef __bf16 bf16x8 __attribute__((ext_vector_type(8)));
typedef unsigned short u16x8 __attribute__((ext_vector_type(8)));
typedef float f32x4 __attribute__((ext_vector_type(4)));
typedef unsigned u32x4 __attribute__((ext_vector_type(4)));

__device__ __forceinline__ unsigned short f2bf(float f) {
  union { float f; unsigned u; } x; x.f = f;
  unsigned r = x.u + 0x7fffu + ((x.u >> 16) & 1u);
  return (unsigned short)(r >> 16);
}
__device__ __forceinline__ float bf2f(unsigned short s) {
  union { unsigned u; float f; } x; x.u = ((unsigned)s) << 16;
  return x.f;
}
__device__ __forceinline__ unsigned pk2(float a, float b) {
  return (unsigned)f2bf(a) | ((unsigned)f2bf(b) << 16);
}
__device__ __forceinline__ void gload16(const void* g, void* l) {
  __builtin_amdgcn_global_load_lds(
      (const __attribute__((address_space(1))) void*)g,
      (__attribute__((address_space(3))) void*)l, 16, 0, 0);
}

// ---------------- prepass: K -> bf16 swizzled tiles, V -> bf16 transposed+swizzled tiles ----------------
__launch_bounds__(256)
__global__ void prep_kernel(const float* __restrict__ kg, const float* __restrict__ vg,
                            unsigned short* __restrict__ kws, unsigned short* __restrict__ vws) {
  const int kt = blockIdx.x, bh = blockIdx.y, t = threadIdx.x;
  const float* ksrc = kg + ((size_t)bh * S_ + kt * 64) * 64;
  const float* vsrc = vg + ((size_t)bh * S_ + kt * 64) * 64;
  unsigned short* kd = kws + (size_t)(bh * 32 + kt) * 4096;
  unsigned short* vd = vws + (size_t)(bh * 32 + kt) * 4096;
  // K: row-major, row-swizzled
#pragma unroll
  for (int p = 0; p < 4; ++p) {
    int row = p * 16 + (t >> 4);
    int col = (t & 15) * 4;
    float4 f = *(const float4*)(ksrc + row * 64 + col);
    ushort4 u = make_ushort4(f2bf(f.x), f2bf(f.y), f2bf(f.z), f2bf(f.w));
    *(ushort4*)(kd + row * 64 + (col ^ ((row & 7) << 3))) = u;
  }
  // V: transposed [d][k], d-row swizzled
  int d0 = (t >> 4) * 4, k0 = (t & 15) * 4;
  float L[4][4];
#pragma unroll
  for (int i = 0; i < 4; ++i)
    *(float4*)L[i] = *(const float4*)(vsrc + (k0 + i) * 64 + d0);
#pragma unroll
  for (int j = 0; j < 4; ++j) {
    int d = d0 + j;
    ushort4 u = make_ushort4(f2bf(L[0][j]), f2bf(L[1][j]), f2bf(L[2][j]), f2bf(L[3][j]));
    *(ushort4*)(vd + d * 64 + (k0 ^ ((d & 7) << 3))) = u;
  }
}

// ---------------- main flash kernel: swapped QK, in-reg softmax, DMA-staged 2-phase pipeline ----------------
// dyn smem layout (bytes): kq dbuf [0,16384) | vt dbuf [16384,32768) | qr [32768,67584) | kadj[2][64] [67584,68096)
#define SMEM_BYTES 68096

__launch_bounds__(256, 2)
__global__ void relattn2_kernel(const float* __restrict__ qg, const float* __restrict__ rel,
                                const int* __restrict__ qinfo, const int* __restrict__ kinfo,
                                const unsigned short* __restrict__ kws,
                                const unsigned short* __restrict__ vws,
                                float* __restrict__ out) {
  extern __shared__ char smem[];
  unsigned short* kq0 = (unsigned short*)smem;
  unsigned short* vt0 = (unsigned short*)(smem + 16384);
  unsigned short* qr_l = (unsigned short*)(smem + 32768);  // [64][272]
  int* kadj = (int*)(smem + 67584);                        // [2][64]

  const int t = threadIdx.x;
  const int lane = t & 63;
  const int w = t >> 6;
  const int lr = lane & 15;
  const int lg = lane >> 4;
  const int qb = blockIdx.x;
  const int bh = blockIdx.y;
  const int b = bh >> 3;
  const int sw = (lr & 7) << 3;
  const float SC = 0.125f * 1.44269504088896340736f;  // 1/sqrt(64) * log2(e)

  const float* qbase = qg + ((size_t)bh * S_ + (size_t)qb * 64) * D_;

  // ---- stage Q (pre-scaled by SC) into kq buf0 ----
#pragma unroll
  for (int p = 0; p < 4; ++p) {
    int row = p * 16 + (t >> 4);
    int col = (t & 15) * 4;
    float4 f = *(const float4*)(qbase + row * 64 + col);
    ushort4 u = make_ushort4(f2bf(f.x * SC), f2bf(f.y * SC), f2bf(f.z * SC), f2bf(f.w * SC));
    *(ushort4*)(kq0 + row * 64 + (col ^ ((row & 7) << 3))) = u;
  }
  __syncthreads();

  // ---- Q fragments (rows w*16+lr -> this wave's own LDS quarter) ----
  bf16x8 qa0, qa1;
  {
    const unsigned short* rb = kq0 + (w * 16 + lr) * 64;
    qa0 = *(const bf16x8*)(rb + ((8 * lg) ^ sw));
    qa1 = *(const bf16x8*)(rb + ((32 + 8 * lg) ^ sw));
  }
  int qa;
  {
    int qv = qinfo[b * S_ + qb * 64 + w * 16 + lr];
    qa = (qv == -1) ? 2 * R_ : qv;
  }
  asm volatile("s_waitcnt lgkmcnt(0)" ::: "memory");  // Q-frag reads done before DMA overwrites quarter

  // ---- issue STAGE(tile 0 -> buf 0); overlaps with qr compute ----
  const size_t tb = (size_t)bh * 32;
  {
    const char* ks = (const char*)(kws + tb * 4096);
    const char* vs = (const char*)(vws + tb * 4096);
    int o0 = w * 2048 + lane * 16;
    gload16(ks + o0, (char*)kq0 + w * 2048);
    gload16(ks + o0 + 1024, (char*)kq0 + w * 2048 + 1024);
    gload16(vs + o0, (char*)vt0 + w * 2048);
    gload16(vs + o0 + 1024, (char*)vt0 + w * 2048 + 1024);
    if (t < 64) {
      int kv = kinfo[b * S_ + t];
      kadj[t] = (kv == -1) ? 3 * R_ : kv;
    }
  }

  // ---- qr tile = Qsc @ rel^T (64x257) via MFMA -> qr_l (bf16, already scaled) ----
  const int qr_rowbase = (w * 16 + 4 * lg) * 272;
#pragma unroll 1
  for (int rt = 0; rt < 17; ++rt) {
    int r = rt * 16 + lr;
    u16x8 t0 = {0, 0, 0, 0, 0, 0, 0, 0};
    u16x8 t1 = {0, 0, 0, 0, 0, 0, 0, 0};
    if (r < 257) {
      const float* rp = rel + r * 64 + 8 * lg;
      float4 fa = *(const float4*)(rp);
      float4 fb = *(const float4*)(rp + 4);
      float4 fc = *(const float4*)(rp + 32);
      float4 fd = *(const float4*)(rp + 36);
      t0 = (u16x8){f2bf(fa.x), f2bf(fa.y), f2bf(fa.z), f2bf(fa.w),
                   f2bf(fb.x), f2bf(fb.y), f2bf(fb.z), f2bf(fb.w)};
      t1 = (u16x8){f2bf(fc.x), f2bf(fc.y), f2bf(fc.z), f2bf(fc.w),
                   f2bf(fd.x), f2bf(fd.y), f2bf(fd.z), f2bf(fd.w)};
    }
    bf16x8 rb0 = __builtin_bit_cast(bf16x8, t0);
    bf16x8 rb1 = __builtin_bit_cast(bf16x8, t1);
    f32x4 acc = {0.f, 0.f, 0.f, 0.f};
    acc = __builtin_amdgcn_mfma_f32_16x16x32_bf16(qa0, rb0, acc, 0, 0, 0);
    acc = __builtin_amdgcn_mfma_f32_16x16x32_bf16(qa1, rb1, acc, 0, 0, 0);
#pragma unroll
    for (int j = 0; j < 4; ++j)
      qr_l[qr_rowbase + j * 272 + rt * 16 + lr] = f2bf(acc[j]);
  }

  __syncthreads();  // drains tile-0 DMA; publishes qr_l

  // ---- flash state (per-lane: one q-row = w*16+lr) ----
  float m_r = -INFINITY, l_r = 0.f;
  f32x4 o_acc[4];
#pragma unroll
  for (int dt = 0; dt < 4; ++dt) o_acc[dt] = (f32x4){0.f, 0.f, 0.f, 0.f};
  const unsigned short* rowptr = qr_l + (w * 16 + lr) * 272;
  const int srcb = (((lg & 1) << 1) << 4) | lr;

  int cur = 0;
#pragma unroll 1
  for (int kt = 0; kt < 32; ++kt) {
    // ---- issue STAGE(kt+1 -> buf[cur^1]) ----
    int ka_next = 0;
    if (kt < 31) {
      const char* ks = (const char*)(kws + (tb + kt + 1) * 4096);
      const char* vs = (const char*)(vws + (tb + kt + 1) * 4096);
      char* kqn = (char*)kq0 + (cur ^ 1) * 8192;
      char* vtn = (char*)vt0 + (cur ^ 1) * 8192;
      int o0 = w * 2048 + lane * 16;
      gload16(ks + o0, kqn + w * 2048);
      gload16(ks + o0 + 1024, kqn + w * 2048 + 1024);
      gload16(vs + o0, vtn + w * 2048);
      gload16(vs + o0 + 1024, vtn + w * 2048 + 1024);
      if (t < 64) ka_next = kinfo[b * S_ + (kt + 1) * 64 + t];
    }

    const unsigned short* kq_c = kq0 + cur * 4096;
    const unsigned short* vt_c = vt0 + cur * 4096;
    const int* kadj_c = kadj + cur * 64;

    // ---- S^T = K Q^T : sfr[st][j] = Ssc[k=st*16+4lg+j][q=lr] ----
    f32x4 sfr[4];
#pragma unroll
    for (int st = 0; st < 4; ++st) {
      const unsigned short* kb = kq_c + (st * 16 + lr) * 64;
      bf16x8 kb0 = *(const bf16x8*)(kb + ((8 * lg) ^ sw));
      bf16x8 kb1 = *(const bf16x8*)(kb + ((32 + 8 * lg) ^ sw));
      f32x4 acc = {0.f, 0.f, 0.f, 0.f};
      acc = __builtin_amdgcn_mfma_f32_16x16x32_bf16(kb0, qa0, acc, 0, 0, 0);
      acc = __builtin_amdgcn_mfma_f32_16x16x32_bf16(kb1, qa1, acc, 0, 0, 0);
      sfr[st] = acc;
    }

    // ---- bias gather + tv ----
    float tv[4][4];
#pragma unroll
    for (int st = 0; st < 4; ++st) {
      int ka4[4];
      *(int4*)ka4 = *(const int4*)&kadj_c[st * 16 + 4 * lg];
#pragma unroll
      for (int j = 0; j < 4; ++j) {
        int dm = ka4[j] - qa;
        dm = min(max(dm, -R_), R_) + R_;
        tv[st][j] = sfr[st][j] + bf2f(rowptr[dm]);
      }
    }

    // ---- online softmax, fully per-lane + 4 shuffles ----
    float mt = tv[0][0];
#pragma unroll
    for (int st = 0; st < 4; ++st)
#pragma unroll
      for (int j = 0; j < 4; ++j) mt = fmaxf(mt, tv[st][j]);
    mt = fmaxf(mt, __shfl_xor(mt, 16));
    mt = fmaxf(mt, __shfl_xor(mt, 32));
    float mnew = fmaxf(m_r, mt);
    float sc2 = exp2f(m_r - mnew);
    float rs = 0.f;
#pragma unroll
    for (int st = 0; st < 4; ++st)
#pragma unroll
      for (int j = 0; j < 4; ++j) {
        float p = exp2f(tv[st][j] - mnew);
        tv[st][j] = p;
        rs += p;
      }
    rs += __shfl_xor(rs, 16);
    rs += __shfl_xor(rs, 32);
    l_r = l_r * sc2 + rs;
    m_r = mnew;
#pragma unroll
    for (int dt = 0; dt < 4; ++dt) o_acc[dt] *= sc2;

    // ---- pack P to bf16 pairs; redistribute to PV B-frag via shfl ----
    unsigned pk[4][2];
#pragma unroll
    for (int st = 0; st < 4; ++st) {
      pk[st][0] = pk2(tv[st][0], tv[st][1]);
      pk[st][1] = pk2(tv[st][2], tv[st][3]);
    }
#pragma unroll
    for (int h = 0; h < 2; ++h) {
      unsigned r0, r1, r2, r3;
      {
        unsigned a0 = (unsigned)__shfl((int)pk[2 * h][0], srcb);
        unsigned b0 = (unsigned)__shfl((int)pk[2 * h + 1][0], srcb);
        r0 = (lg & 2) ? b0 : a0;
        unsigned a1 = (unsigned)__shfl((int)pk[2 * h][1], srcb);
        unsigned b1 = (unsigned)__shfl((int)pk[2 * h + 1][1], srcb);
        r1 = (lg & 2) ? b1 : a1;
        unsigned a2 = (unsigned)__shfl((int)pk[2 * h][0], srcb + 16);
        unsigned b2 = (unsigned)__shfl((int)pk[2 * h + 1][0], srcb + 16);
        r2 = (lg & 2) ? b2 : a2;
        unsigned a3 = (unsigned)__shfl((int)pk[2 * h][1], srcb + 16);
        unsigned b3 = (unsigned)__shfl((int)pk[2 * h + 1][1], srcb + 16);
        r3 = (lg & 2) ? b3 : a3;
      }
      u32x4 rv = {r0, r1, r2, r3};
      bf16x8 pb = __builtin_bit_cast(bf16x8, rv);
      // ---- O^T += V^T P : o_acc[dt][j] = O[q=lr][d=dt*16+4lg+j] ----
#pragma unroll
      for (int dt = 0; dt < 4; ++dt) {
        const unsigned short* vb = vt_c + (dt * 16 + lr) * 64;
        bf16x8 va = *(const bf16x8*)(vb + ((h * 32 + 8 * lg) ^ sw));
        o_acc[dt] = __builtin_amdgcn_mfma_f32_16x16x32_bf16(va, pb, o_acc[dt], 0, 0, 0);
      }
    }

    // ---- late kadj write (global load had whole tile to land) ----
    if (kt < 31 && t < 64) kadj[(cur ^ 1) * 64 + t] = (ka_next == -1) ? 3 * R_ : ka_next;
    __syncthreads();  // drains next-tile DMA; guards buffer swap
    cur ^= 1;
  }

  // ---- epilogue ----
  float inv = 1.f / l_r;
  float* obase = out + ((size_t)bh * S_ + (size_t)(qb * 64 + w * 16 + lr)) * 64;
#pragma unroll
  for (int dt = 0; dt < 4; ++dt) {
    f32x4 ov = o_acc[dt] * inv;
    *(f32x4*)(obase + dt * 16 + 4 * lg) = ov;
  }
}

// ---------------- fallback (R1 kernel, used only if ws too small) ----------------
__launch_bounds__(256, 2)
__global__ void relattn_kernel(const float* __restrict__ qg, const float* __restrict__ kg,
                               const float* __restrict__ vg, const float* __restrict__ rel,
                               const int* __restrict__ qinfo, const int* __restrict__ kinfo,
                               float* __restrict__ out) {
  __shared__ __align__(16) unsigned short kq_lds[64 * 64];
  __shared__ __align__(16) unsigned short vt_lds[64 * 64];
  __shared__ __align__(16) unsigned short p_lds[4 * 16 * 64];
  __shared__ __align__(16) unsigned short qr_lds[64 * 272];
  __shared__ int kadj_lds[64];
  __shared__ int qadj_lds[64];
  const int t = threadIdx.x, lane = t & 63, w = t >> 6, lr = lane & 15, lg = lane >> 4;
  const int qb = blockIdx.x, bh = blockIdx.y, b = bh >> 3;
  const float* qbase = qg + ((size_t)bh * S_ + (size_t)qb * 64) * D_;
  const float* kbase = kg + (size_t)bh * S_ * D_;
  const float* vbase = vg + (size_t)bh * S_ * D_;
#pragma unroll
  for (int p = 0; p < 4; ++p) {
    int row = p * 16 + (t >> 4), col = (t & 15) * 4;
    const float4 f = *(const float4*)(qbase + row * 64 + col);
    ushort4 u = make_ushort4(f2bf(f.x), f2bf(f.y), f2bf(f.z), f2bf(f.w));
    *(ushort4*)(&kq_lds[row * 64 + (col ^ ((row & 7) << 3))]) = u;
  }
  if (t < 64) { int qa = qinfo[b * S_ + qb * 64 + t]; qadj_lds[t] = (qa == -1) ? 2 * R_ : qa; }
  __syncthreads();
  bf16x8 qa0, qa1;
  {
    const unsigned short* rbase = &kq_lds[(w * 16 + lr) * 64];
    qa0 = *(const bf16x8*)(rbase + ((8 * lg) ^ ((lr & 7) << 3)));
    qa1 = *(const bf16x8*)(rbase + ((32 + 8 * lg) ^ ((lr & 7) << 3)));
  }
  int qadj_r[4];
#pragma unroll
  for (int j = 0; j < 4; ++j) qadj_r[j] = qadj_lds[w * 16 + 4 * lg + j];
  const int qr_rowbase = (w * 16 + 4 * lg) * 272;
#pragma unroll 1
  for (int rt = 0; rt < 17; ++rt) {
    int r = rt * 16 + lr;
    u16x8 t0 = {0,0,0,0,0,0,0,0}, t1 = {0,0,0,0,0,0,0,0};
    if (r < 257) {
      const float* rp = rel + r * 64 + 8 * lg;
      float4 fa = *(const float4*)(rp), fb = *(const float4*)(rp + 4);
      float4 fc = *(const float4*)(rp + 32), fd = *(const float4*)(rp + 36);
      t0 = (u16x8){f2bf(fa.x), f2bf(fa.y), f2bf(fa.z), f2bf(fa.w), f2bf(fb.x), f2bf(fb.y), f2bf(fb.z), f2bf(fb.w)};
      t1 = (u16x8){f2bf(fc.x), f2bf(fc.y), f2bf(fc.z), f2bf(fc.w), f2bf(fd.x), f2bf(fd.y), f2bf(fd.z), f2bf(fd.w)};
    }
    bf16x8 rb0 = __builtin_bit_cast(bf16x8, t0), rb1 = __builtin_bit_cast(bf16x8, t1);
    f32x4 acc = {0.f, 0.f, 0.f, 0.f};
    acc = __builtin_amdgcn_mfma_f32_16x16x32_bf16(qa0, rb0, acc, 0, 0, 0);
    acc = __builtin_amdgcn_mfma_f32_16x16x32_bf16(qa1, rb1, acc, 0, 0, 0);
#pragma unroll
    for (int j = 0; j < 4; ++j) qr_lds[qr_rowbase + j * 272 + rt * 16 + lr] = f2bf(acc[j]);
  }
  float m_r[4], l_r[4];
  f32x4 o_acc[4];
#pragma unroll
  for (int j = 0; j < 4; ++j) { m_r[j] = -INFINITY; l_r[j] = 0.f; }
#pragma unroll
  for (int dt = 0; dt < 4; ++dt) o_acc[dt] = (f32x4){0.f, 0.f, 0.f, 0.f};
  const float SC = 0.125f * 1.44269504088896340736f;
  unsigned short* p_w = &p_lds[w * 16 * 64];
  for (int kt = 0; kt < 32; ++kt) {
    __syncthreads();
    const float* ksrc = kbase + (size_t)(kt * 64) * 64;
    const float* vsrc = vbase + (size_t)(kt * 64) * 64;
#pragma unroll
    for (int p = 0; p < 4; ++p) {
      int row = p * 16 + (t >> 4), col = (t & 15) * 4;
      float4 f = *(const float4*)(ksrc + row * 64 + col);
      ushort4 u = make_ushort4(f2bf(f.x), f2bf(f.y), f2bf(f.z), f2bf(f.w));
      *(ushort4*)(&kq_lds[row * 64 + (col ^ ((row & 7) << 3))]) = u;
      float4 fv = *(const float4*)(vsrc + row * 64 + col);
      vt_lds[(col + 0) * 64 + (row ^ (((col + 0) & 7) << 3))] = f2bf(fv.x);
      vt_lds[(col + 1) * 64 + (row ^ (((col + 1) & 7) << 3))] = f2bf(fv.y);
      vt_lds[(col + 2) * 64 + (row ^ (((col + 2) & 7) << 3))] = f2bf(fv.z);
      vt_lds[(col + 3) * 64 + (row ^ (((col + 3) & 7) << 3))] = f2bf(fv.w);
    }
    if (t < 64) { int ka = kinfo[b * S_ + kt * 64 + t]; kadj_lds[t] = (ka == -1) ? 3 * R_ : ka; }
    __syncthreads();
    f32x4 sfr[4];
#pragma unroll
    for (int st = 0; st < 4; ++st) {
      const unsigned short* kb = &kq_lds[(st * 16 + lr) * 64];
      bf16x8 kb0 = *(const bf16x8*)(kb + ((8 * lg) ^ ((lr & 7) << 3)));
      bf16x8 kb1 = *(const bf16x8*)(kb + ((32 + 8 * lg) ^ ((lr & 7) << 3)));
      f32x4 acc = {0.f, 0.f, 0.f, 0.f};
      acc = __builtin_amdgcn_mfma_f32_16x16x32_bf16(qa0, kb0, acc, 0, 0, 0);
      acc = __builtin_amdgcn_mfma_f32_16x16x32_bf16(qa1, kb1, acc, 0, 0, 0);
      sfr[st] = acc;
    }
    float tv[4][4];
#pragma unroll
    for (int st = 0; st < 4; ++st) {
      int ka = kadj_lds[st * 16 + lr];
#pragma unroll
      for (int j = 0; j < 4; ++j) {
        int dm = ka - qadj_r[j];
        dm = min(max(dm, -R_), R_) + R_;
        tv[st][j] = (sfr[st][j] + bf2f(qr_lds[qr_rowbase + j * 272 + dm])) * SC;
      }
    }
#pragma unroll
    for (int j = 0; j < 4; ++j) {
      float mx = fmaxf(fmaxf(tv[0][j], tv[1][j]), fmaxf(tv[2][j], tv[3][j]));
      mx = fmaxf(mx, __shfl_xor(mx, 1)); mx = fmaxf(mx, __shfl_xor(mx, 2));
      mx = fmaxf(mx, __shfl_xor(mx, 4)); mx = fmaxf(mx, __shfl_xor(mx, 8));
      float mnew = fmaxf(m_r[j], mx);
      float scale = exp2f(m_r[j] - mnew);
      float rs = 0.f;
#pragma unroll
      for (int st = 0; st < 4; ++st) { float p = exp2f(tv[st][j] - mnew); tv[st][j] = p; rs += p; }
      rs += __shfl_xor(rs, 1); rs += __shfl_xor(rs, 2);
      rs += __shfl_xor(rs, 4); rs += __shfl_xor(rs, 8);
      l_r[j] = l_r[j] * scale + rs;
      m_r[j] = mnew;
#pragma unroll
      for (int dt = 0; dt < 4; ++dt) o_acc[dt][j] *= scale;
    }
#pragma unroll
    for (int st = 0; st < 4; ++st)
#pragma unroll
      for (int j = 0; j < 4; ++j) {
        int row = 4 * lg + j, col = st * 16 + lr;
        p_w[row * 64 + (col ^ ((row & 7) << 3))] = f2bf(tv[st][j]);
      }
    bf16x8 pa0, pa1;
    {
      const unsigned short* pb = &p_w[lr * 64];
      pa0 = *(const bf16x8*)(pb + ((8 * lg) ^ ((lr & 7) << 3)));
      pa1 = *(const bf16x8*)(pb + ((32 + 8 * lg) ^ ((lr & 7) << 3)));
    }
#pragma unroll
    for (int dt = 0; dt < 4; ++dt) {
      const unsigned short* vb = &vt_lds[(dt * 16 + lr) * 64];
      bf16x8 vb0 = *(const bf16x8*)(vb + ((8 * lg) ^ ((lr & 7) << 3)));
      bf16x8 vb1 = *(const bf16x8*)(vb + ((32 + 8 * lg) ^ ((lr & 7) << 3)));
      o_acc[dt] = __builtin_amdgcn_mfma_f32_16x16x32_bf16(pa0, vb0, o_acc[dt], 0, 0, 0);
      o_acc[dt] = __builtin_amdgcn_mfma_f32_16x16x32_bf16(pa1, vb1, o_acc[dt], 0, 0, 0);
    }
  }
  float* obase = out + ((size_t)bh * S_ + (size_t)(qb * 64 + w * 16)) * 64;
#pragma unroll
  for (int j = 0; j < 4; ++j) {
    float inv = 1.f / l_r[j];
    int row = 4 * lg + j;
#pragma unroll
    for (int dt = 0; dt < 4; ++dt) obase[row * 64 + dt * 16 + lr] = o_acc[dt][j] * inv;
  }
}

extern "C" void kernel_launch(void* const* d_in, const int* in_sizes, int n_in,
                              void* d_out, int out_size, void* d_ws, size_t ws_size,
                              hipStream_t stream) {
  const float* q = (const float*)d_in[0];
  const float* k = (const float*)d_in[1];
  const float* v = (const float*)d_in[2];
  const float* rel = (const float*)d_in[3];
  const int* qi = (const int*)d_in[4];
  const int* ki = (const int*)d_in[5];
  float* out = (float*)d_out;

  if (ws_size >= (size_t)8 * 1024 * 1024 + 512) {
    unsigned short* kws = (unsigned short*)d_ws;
    unsigned short* vws = (unsigned short*)((char*)d_ws + 4 * 1024 * 1024);
    prep_kernel<<<dim3(32, 16), dim3(256), 0, stream>>>(k, v, kws, vws);
    hipFuncSetAttribute((const void*)relattn2_kernel,
                        hipFuncAttributeMaxDynamicSharedMemorySize, SMEM_BYTES);
    relattn2_kernel<<<dim3(S_ / 64, B_ * H_), dim3(256), SMEM_BYTES, stream>>>(
        q, rel, qi, ki, kws, vws, out);
  } else {
    relattn_kernel<<<dim3(S_ / 64, B_ * H_), dim3(256), 0, stream>>>(q, k, v, rel, qi, ki, out);
  }
}